// Round 2
// baseline (207.458 us; speedup 1.0000x reference)
//
#include <hip/hip_runtime.h>

// Problem constants (B, L, H, E) from the reference
#define Bb 2
#define Ls 2048
#define Hh 16
#define Ee 64

#define QT 128   // q rows per block (4 waves x 32)
#define KT 64    // kv rows per tile

typedef __fp16 f16;
typedef __attribute__((ext_vector_type(2)))  __fp16 f16x2;
typedef __attribute__((ext_vector_type(8)))  __fp16 f16x8;
typedef __attribute__((ext_vector_type(16))) float  f32x16;

union Frag  { f16x8 v; f16x2 h[4]; unsigned int u[4]; };
union U32H2 { f16x2 h; unsigned int u; };

__device__ __forceinline__ f16x2 pkrtz(float a, float b) {
  return __builtin_amdgcn_cvt_pkrtz(a, b);
}
__device__ __forceinline__ f32x16 mfma16(f16x8 a, f16x8 b, f32x16 c) {
  return __builtin_amdgcn_mfma_f32_32x32x16_f16(a, b, c, 0, 0, 0);
}
__device__ __forceinline__ f32x16 zero16() {
  f32x16 z;
#pragma unroll
  for (int i = 0; i < 16; ++i) z[i] = 0.f;
  return z;
}

// logits = 8 * (q.k)  ->  exp(8S) = exp2(S * 8*log2(e))
#define SC 11.541560327111707f

__launch_bounds__(256, 2)
__global__ void fattn(const float* __restrict__ Q, const float* __restrict__ K,
                      const float* __restrict__ V, float* __restrict__ O) {
  // LDS: Khi[64][64] f16 (8KB) | Klo (8KB) | Vt[e=64][kv pairs] f16 (8KB)
  __shared__ __align__(16) char lds[24576];
  char* Khi = lds;
  char* Klo = lds + 8192;
  char* Vt  = lds + 16384;

  const int tid  = threadIdx.x;
  const int lane = tid & 63;
  const int wid  = tid >> 6;
  const int h2   = lane >> 5;   // wave half
  const int qc   = lane & 31;   // owned q-row (S^T col) / e-col (O col) / kv-row (K A-frag)
  const int bid  = blockIdx.x;
  const int qt   = bid & 15;
  const int bh   = bid >> 4;
  const int b    = bh >> 4;
  const int h    = bh & 15;

  const int q0   = qt * QT;
  const int q0w  = q0 + wid * 32;
  const int qrow = q0w + qc;

  // ---- Q fragments (B-operand: n = lane&31 = q-row, k = 8*h2 + i per 16-chunk), f16 hi/lo
  f16x8 qh[4], ql[4];
  {
    const float* qp = Q + (((size_t)(b * Ls + qrow) * Hh) + h) * Ee + h2 * 8;
#pragma unroll
    for (int c = 0; c < 4; ++c) {
      float x[8];
      *(float4*)&x[0] = *(const float4*)(qp + c * 16);
      *(float4*)&x[4] = *(const float4*)(qp + c * 16 + 4);
      Frag fh, fl;
#pragma unroll
      for (int j = 0; j < 4; ++j) {
        f16x2 hi = pkrtz(x[2 * j], x[2 * j + 1]);
        fl.h[j] = pkrtz(x[2 * j] - (float)hi[0], x[2 * j + 1] - (float)hi[1]);
        fh.h[j] = hi;
      }
      qh[c] = fh.v;
      ql[c] = fl.v;
    }
  }

  f32x16 o0 = zero16(), o1 = zero16();
  float m = -3.0e38f, l = 0.f;

  const int NT = (q0 + QT) / KT;

  for (int t = 0; t < NT; ++t) {
    const int kb = t * KT;
    __syncthreads();

    // ---- stage K tile as f16 hi/lo with XOR swizzle (byte ^= (row&7)<<4)
    {
      const int r   = tid >> 2;            // 0..63 kv row
      const int cbe = (tid & 3) * 16;      // element col base (16 floats/thread)
      const float* kp = K + (((size_t)(b * Ls + kb + r) * Hh) + h) * Ee + cbe;
      float x[16];
      *(float4*)&x[0]  = *(const float4*)(kp);
      *(float4*)&x[4]  = *(const float4*)(kp + 4);
      *(float4*)&x[8]  = *(const float4*)(kp + 8);
      *(float4*)&x[12] = *(const float4*)(kp + 12);
      Frag fh0, fl0, fh1, fl1;
#pragma unroll
      for (int j = 0; j < 4; ++j) {
        f16x2 hi0 = pkrtz(x[2 * j], x[2 * j + 1]);
        fl0.h[j] = pkrtz(x[2 * j] - (float)hi0[0], x[2 * j + 1] - (float)hi0[1]);
        fh0.h[j] = hi0;
        f16x2 hi1 = pkrtz(x[8 + 2 * j], x[8 + 2 * j + 1]);
        fl1.h[j] = pkrtz(x[8 + 2 * j] - (float)hi1[0], x[8 + 2 * j + 1] - (float)hi1[1]);
        fh1.h[j] = hi1;
      }
      const int sw = (r & 7) << 4;
      char* dh = Khi + r * 128;
      char* dl = Klo + r * 128;
      *(f16x8*)(dh + ((cbe * 2) ^ sw))      = fh0.v;
      *(f16x8*)(dh + ((cbe * 2 + 16) ^ sw)) = fh1.v;
      *(f16x8*)(dl + ((cbe * 2) ^ sw))      = fl0.v;
      *(f16x8*)(dl + ((cbe * 2 + 16) ^ sw)) = fl1.v;
    }
    // ---- stage V transposed: Vt[e][kv/2] = pack(V[kv][e], V[kv+1][e]), swizzled
    {
      const int kv0 = (tid & 31) * 2;
      const int ec  = tid >> 5;            // 0..7
      const float* vp = V + (((size_t)(b * Ls + kb + kv0) * Hh) + h) * Ee + ec * 8;
      float y0[8], y1[8];
      *(float4*)&y0[0] = *(const float4*)(vp);
      *(float4*)&y0[4] = *(const float4*)(vp + 4);
      *(float4*)&y1[0] = *(const float4*)(vp + Hh * Ee);
      *(float4*)&y1[4] = *(const float4*)(vp + Hh * Ee + 4);
#pragma unroll
      for (int j = 0; j < 8; ++j) {
        U32H2 pr;
        pr.h = pkrtz(y0[j], y1[j]);
        const int e = ec * 8 + j;
        *(unsigned int*)(Vt + e * 128 + ((kv0 * 2) ^ ((e & 7) << 4))) = pr.u;
      }
    }
    __syncthreads();

    if (kb > q0w + 31) continue;  // tile fully above this wave's diagonal

    // ---- S^T = K * Q^T (two 32-kv subtiles), f16 hi/lo (3 MFMAs/chunk)
    f32x16 s0 = zero16(), s1 = zero16();
    {
      const int sw = (qc & 7) << 4;
#pragma unroll
      for (int st = 0; st < 2; ++st) {
        const char* kbh = Khi + (st * 32 + qc) * 128;
        const char* kbl = Klo + (st * 32 + qc) * 128;
        f32x16 acc = st ? s1 : s0;
#pragma unroll
        for (int c = 0; c < 4; ++c) {
          const int off = ((c << 5) + (h2 << 4)) ^ sw;
          f16x8 ah = *(const f16x8*)(kbh + off);
          f16x8 al = *(const f16x8*)(kbl + off);
          acc = mfma16(ah, qh[c], acc);
          acc = mfma16(ah, ql[c], acc);
          acc = mfma16(al, qh[c], acc);
        }
        if (st) s1 = acc; else s0 = acc;
      }
    }

    float p[32];
#pragma unroll
    for (int r = 0; r < 16; ++r) { p[r] = s0[r]; p[16 + r] = s1[r]; }

    // causal mask (only tiles overlapping the diagonal)
    if (kb + KT - 1 > q0w) {
#pragma unroll
      for (int st = 0; st < 2; ++st)
#pragma unroll
        for (int r = 0; r < 16; ++r) {
          const int kv = kb + st * 32 + ((r & 3) + 8 * (r >> 2) + 4 * h2);
          if (kv > qrow) p[st * 16 + r] = -3.0e38f;
        }
    }

    // online softmax (row = qc, both halves hold the full row across lane^32)
    float tm = p[0];
#pragma unroll
    for (int i = 1; i < 32; ++i) tm = fmaxf(tm, p[i]);
    tm = fmaxf(tm, __shfl_xor(tm, 32));
    const float mnew = fmaxf(m, tm);
    if (__any(mnew > m)) {
      const float corr = __builtin_amdgcn_exp2f((m - mnew) * SC);
      l *= corr;
#pragma unroll
      for (int r = 0; r < 16; ++r) {
        const float cr = __shfl(corr, (r & 3) + 8 * (r >> 2) + 4 * h2);
        o0[r] *= cr;
        o1[r] *= cr;
      }
      m = mnew;
    }
    const float base = m * SC;
    float ps = 0.f;
#pragma unroll
    for (int i = 0; i < 32; ++i) {
      p[i] = __builtin_amdgcn_exp2f(p[i] * SC - base);
      ps += p[i];
    }
    ps += __shfl_xor(ps, 32);
    l += ps;

    // ---- pack P -> f16 A-fragments (cross-half exchange, 2 shfl per chunk)
    f16x8 pa[4];
#pragma unroll
    for (int st = 0; st < 2; ++st) {
      unsigned u[8];
#pragma unroll
      for (int g = 0; g < 4; ++g) {
        U32H2 a, bb;
        a.h  = pkrtz(p[st * 16 + 4 * g],     p[st * 16 + 4 * g + 1]);
        bb.h = pkrtz(p[st * 16 + 4 * g + 2], p[st * 16 + 4 * g + 3]);
        u[2 * g]     = a.u;
        u[2 * g + 1] = bb.u;
      }
#pragma unroll
      for (int cp = 0; cp < 2; ++cp) {
        const unsigned ua0 = u[4 * cp], ua1 = u[4 * cp + 1];
        const unsigned ub0 = u[4 * cp + 2], ub1 = u[4 * cp + 3];
        const unsigned t0 = (unsigned)__shfl_xor((int)(h2 ? ua0 : ub0), 32);
        const unsigned t1 = (unsigned)__shfl_xor((int)(h2 ? ua1 : ub1), 32);
        Frag f;
        f.u[0] = h2 ? t0 : ua0;
        f.u[1] = h2 ? t1 : ua1;
        f.u[2] = h2 ? ub0 : t0;
        f.u[3] = h2 ? ub1 : t1;
        pa[st * 2 + cp] = f.v;
      }
    }

    // ---- PV: O[q][e] += P * V  (B from transposed V, contiguous b128)
    {
      const int sw = (qc & 7) << 4;
#pragma unroll
      for (int c = 0; c < 4; ++c) {
        const int off = ((c << 5) + (h2 << 4)) ^ sw;
        const f16x8 vb0 = *(const f16x8*)(Vt + (qc)      * 128 + off);
        const f16x8 vb1 = *(const f16x8*)(Vt + (32 + qc) * 128 + off);
        o0 = mfma16(pa[c], vb0, o0);
        o1 = mfma16(pa[c], vb1, o1);
      }
    }
  }

  // ---- epilogue: normalize and store
  const float inv = 1.0f / l;
#pragma unroll
  for (int r = 0; r < 16; ++r) {
    const int row = (r & 3) + 8 * (r >> 2) + 4 * h2;
    const float iv = __shfl(inv, row);
    float* op = O + (((size_t)(b * Ls + q0w + row) * Hh) + h) * Ee;
    op[qc]      = o0[r] * iv;
    op[32 + qc] = o1[r] * iv;
  }
}

extern "C" void kernel_launch(void* const* d_in, const int* in_sizes, int n_in,
                              void* d_out, int out_size, void* d_ws, size_t ws_size,
                              hipStream_t stream) {
  const float* Q = (const float*)d_in[0];
  const float* K = (const float*)d_in[1];
  const float* V = (const float*)d_in[2];
  float* O = (float*)d_out;
  (void)in_sizes; (void)n_in; (void)out_size; (void)d_ws; (void)ws_size;
  dim3 grid(Bb * Hh * (Ls / QT));  // 512 blocks, 4 waves each
  fattn<<<grid, dim3(256), 0, stream>>>(Q, K, V, O);
}

// Round 3
// 164.836 us; speedup vs baseline: 1.2586x; 1.2586x over previous
//
#include <hip/hip_runtime.h>

// Problem constants (B, L, H, E) from the reference
#define Bb 2
#define Ls 2048
#define Hh 16
#define Ee 64

#define QT 128   // q rows per block (4 waves x 32)
#define KT 64    // kv rows per tile
#define BUFB 24576  // bytes per LDS buffer (Khi 8K | Klo 8K | Vt 8K)

typedef __fp16 f16;
typedef __attribute__((ext_vector_type(2)))  __fp16 f16x2;
typedef __attribute__((ext_vector_type(8)))  __fp16 f16x8;
typedef __attribute__((ext_vector_type(16))) float  f32x16;

union Frag  { f16x8 v; f16x2 h[4]; unsigned int u[4]; };
union U32H2 { f16x2 h; unsigned int u; };

__device__ __forceinline__ f16x2 pkrtz(float a, float b) {
  return __builtin_amdgcn_cvt_pkrtz(a, b);
}
__device__ __forceinline__ f32x16 mfma16(f16x8 a, f16x8 b, f32x16 c) {
  return __builtin_amdgcn_mfma_f32_32x32x16_f16(a, b, c, 0, 0, 0);
}
__device__ __forceinline__ f32x16 zero16() {
  f32x16 z;
#pragma unroll
  for (int i = 0; i < 16; ++i) z[i] = 0.f;
  return z;
}

// logits = 8 * (q.k)  ->  exp(8S) = exp2(S * 8*log2(e))
#define SC 11.541560327111707f

__launch_bounds__(256, 2)
__global__ void fattn(const float* __restrict__ Q, const float* __restrict__ K,
                      const float* __restrict__ V, float* __restrict__ O) {
  __shared__ __align__(16) char lds[2 * BUFB];

  const int tid  = threadIdx.x;
  const int lane = tid & 63;
  const int wid  = tid >> 6;
  const int h2   = lane >> 5;
  const int qc   = lane & 31;
  const int bid  = blockIdx.x;

  // complementary pairing: co-resident blocks (c, c+256) get qt summing to 15
  const int bh  = bid & 31;
  const int qtx = bid >> 5;                 // 0..15
  const int qt  = (qtx < 8) ? qtx : 23 - qtx;
  const int b   = bh >> 4;
  const int h   = bh & 15;

  const int q0   = qt * QT;
  const int q0w  = q0 + wid * 32;
  const int qrow = q0w + qc;

  // ---- Q fragments (B-operand), f16 hi/lo
  f16x8 qh[4], ql[4];
  {
    const float* qp = Q + (((size_t)(b * Ls + qrow) * Hh) + h) * Ee + h2 * 8;
#pragma unroll
    for (int c = 0; c < 4; ++c) {
      float x[8];
      *(float4*)&x[0] = *(const float4*)(qp + c * 16);
      *(float4*)&x[4] = *(const float4*)(qp + c * 16 + 4);
      Frag fh, fl;
#pragma unroll
      for (int j = 0; j < 4; ++j) {
        f16x2 hi = pkrtz(x[2 * j], x[2 * j + 1]);
        fl.h[j] = pkrtz(x[2 * j] - (float)hi[0], x[2 * j + 1] - (float)hi[1]);
        fh.h[j] = hi;
      }
      qh[c] = fh.v;
      ql[c] = fl.v;
    }
  }

  // ---- staging address bases (per-thread roles fixed)
  const int r    = tid >> 2;            // K row 0..63
  const int cbe  = (tid & 3) * 16;      // K element col base
  const int kv0  = (tid & 31) * 2;      // V kv-pair base
  const int ec   = tid >> 5;            // V e-col block 0..7
  const float* kp0 = K + (((size_t)(b * Ls + r) * Hh) + h) * Ee + cbe;
  const float* vp0 = V + (((size_t)(b * Ls + kv0) * Hh) + h) * Ee + ec * 8;
  const int rowstride = Hh * Ee;        // 1024 floats per seq position

  float4 ka0, ka1, ka2, ka3, va0, va1, vb0, vb1;  // prefetch registers

#define STAGE_LOAD(KB)                                              \
  {                                                                 \
    const float* kp = kp0 + (size_t)(KB) * rowstride;               \
    ka0 = *(const float4*)(kp);                                     \
    ka1 = *(const float4*)(kp + 4);                                 \
    ka2 = *(const float4*)(kp + 8);                                 \
    ka3 = *(const float4*)(kp + 12);                                \
    const float* vp = vp0 + (size_t)(KB) * rowstride;               \
    va0 = *(const float4*)(vp);                                     \
    va1 = *(const float4*)(vp + 4);                                 \
    vb0 = *(const float4*)(vp + rowstride);                         \
    vb1 = *(const float4*)(vp + rowstride + 4);                     \
  }

#define STAGE_WRITE(BUF)                                            \
  {                                                                 \
    char* Khi = (BUF);                                              \
    char* Klo = (BUF) + 8192;                                       \
    char* Vt  = (BUF) + 16384;                                      \
    float x[16];                                                    \
    *(float4*)&x[0]  = ka0; *(float4*)&x[4]  = ka1;                 \
    *(float4*)&x[8]  = ka2; *(float4*)&x[12] = ka3;                 \
    Frag fh0, fl0, fh1, fl1;                                        \
    _Pragma("unroll")                                               \
    for (int j = 0; j < 4; ++j) {                                   \
      f16x2 hi0 = pkrtz(x[2 * j], x[2 * j + 1]);                    \
      fl0.h[j] = pkrtz(x[2 * j] - (float)hi0[0],                    \
                       x[2 * j + 1] - (float)hi0[1]);               \
      fh0.h[j] = hi0;                                               \
      f16x2 hi1 = pkrtz(x[8 + 2 * j], x[8 + 2 * j + 1]);            \
      fl1.h[j] = pkrtz(x[8 + 2 * j] - (float)hi1[0],                \
                       x[8 + 2 * j + 1] - (float)hi1[1]);           \
      fh1.h[j] = hi1;                                               \
    }                                                               \
    const int sw = (r & 7) << 4;                                    \
    char* dh = Khi + r * 128;                                       \
    char* dl = Klo + r * 128;                                       \
    *(f16x8*)(dh + ((cbe * 2) ^ sw))      = fh0.v;                  \
    *(f16x8*)(dh + ((cbe * 2 + 16) ^ sw)) = fh1.v;                  \
    *(f16x8*)(dl + ((cbe * 2) ^ sw))      = fl0.v;                  \
    *(f16x8*)(dl + ((cbe * 2 + 16) ^ sw)) = fl1.v;                  \
    float y0[8], y1[8];                                             \
    *(float4*)&y0[0] = va0; *(float4*)&y0[4] = va1;                 \
    *(float4*)&y1[0] = vb0; *(float4*)&y1[4] = vb1;                 \
    _Pragma("unroll")                                               \
    for (int j = 0; j < 8; ++j) {                                   \
      U32H2 pr;                                                     \
      pr.h = pkrtz(y0[j], y1[j]);                                   \
      const int e = ec * 8 + j;                                     \
      *(unsigned int*)(Vt + e * 128 + ((kv0 * 2) ^ ((e & 7) << 4))) = pr.u; \
    }                                                               \
  }

  f32x16 o0 = zero16(), o1 = zero16();
  float m = -3.0e38f, l = 0.f;

  const int NT = (q0 + QT) / KT;

  // prologue: stage tile 0
  STAGE_LOAD(0);
  STAGE_WRITE(lds);
  __syncthreads();
  int cur = 0;

  for (int t = 0; t < NT; ++t) {
    const int kb = t * KT;
    const bool pf = (t + 1 < NT);
    if (pf) STAGE_LOAD(kb + KT);   // issue next tile's loads before compute

    if (kb <= q0w + 31) {
      char* bufc = lds + cur * BUFB;
      char* Khi = bufc;
      char* Klo = bufc + 8192;
      char* Vt  = bufc + 16384;

      // ---- S^T = K * Q^T, hi/lo split with 4 independent MFMA chains
      f32x16 s0, s1;
      {
        const int sw = (qc & 7) << 4;
        const char* kbh0 = Khi + qc * 128;
        const char* kbl0 = Klo + qc * 128;
        const char* kbh1 = Khi + (32 + qc) * 128;
        const char* kbl1 = Klo + (32 + qc) * 128;
        f32x16 a0h = zero16(), a0l = zero16(), a1h = zero16(), a1l = zero16();
        __builtin_amdgcn_s_setprio(1);
#pragma unroll
        for (int c = 0; c < 4; ++c) {
          const int off = ((c << 5) + (h2 << 4)) ^ sw;
          f16x8 ah0 = *(const f16x8*)(kbh0 + off);
          f16x8 al0 = *(const f16x8*)(kbl0 + off);
          f16x8 ah1 = *(const f16x8*)(kbh1 + off);
          f16x8 al1 = *(const f16x8*)(kbl1 + off);
          a0h = mfma16(ah0, qh[c], a0h);
          a1h = mfma16(ah1, qh[c], a1h);
          a0l = mfma16(ah0, ql[c], a0l);
          a1l = mfma16(ah1, ql[c], a1l);
          a0l = mfma16(al0, qh[c], a0l);
          a1l = mfma16(al1, qh[c], a1l);
        }
        __builtin_amdgcn_s_setprio(0);
#pragma unroll
        for (int i = 0; i < 16; ++i) { s0[i] = a0h[i] + a0l[i]; s1[i] = a1h[i] + a1l[i]; }
      }

      float p[32];
#pragma unroll
      for (int rr = 0; rr < 16; ++rr) { p[rr] = s0[rr]; p[16 + rr] = s1[rr]; }

      // causal mask (diagonal tiles only)
      if (kb + KT - 1 > q0w) {
#pragma unroll
        for (int st = 0; st < 2; ++st)
#pragma unroll
          for (int rr = 0; rr < 16; ++rr) {
            const int kv = kb + st * 32 + ((rr & 3) + 8 * (rr >> 2) + 4 * h2);
            if (kv > qrow) p[st * 16 + rr] = -3.0e38f;
          }
      }

      // ---- online softmax, tree reductions
      float w[16];
#pragma unroll
      for (int i = 0; i < 16; ++i) w[i] = fmaxf(p[i], p[i + 16]);
#pragma unroll
      for (int i = 0; i < 8; ++i) w[i] = fmaxf(w[i], w[i + 8]);
#pragma unroll
      for (int i = 0; i < 4; ++i) w[i] = fmaxf(w[i], w[i + 4]);
      w[0] = fmaxf(fmaxf(w[0], w[1]), fmaxf(w[2], w[3]));
      float tm = fmaxf(w[0], __shfl_xor(w[0], 32));

      // slack-gated rescale (P bounded by 2^11.5, fine in f16)
      if (__any(tm > m + 1.0f)) {
        const float mnew = fmaxf(m, tm);
        const float corr = __builtin_amdgcn_exp2f((m - mnew) * SC);
        l *= corr;
#pragma unroll
        for (int rr = 0; rr < 16; ++rr) {
          const float cr = __shfl(corr, (rr & 3) + 8 * (rr >> 2) + 4 * h2);
          o0[rr] *= cr;
          o1[rr] *= cr;
        }
        m = mnew;
      }
      const float base = m * SC;
#pragma unroll
      for (int i = 0; i < 32; ++i) p[i] = __builtin_amdgcn_exp2f(p[i] * SC - base);
      float z[16];
#pragma unroll
      for (int i = 0; i < 16; ++i) z[i] = p[i] + p[i + 16];
#pragma unroll
      for (int i = 0; i < 8; ++i) z[i] += z[i + 8];
#pragma unroll
      for (int i = 0; i < 4; ++i) z[i] += z[i + 4];
      float ps = (z[0] + z[1]) + (z[2] + z[3]);
      ps += __shfl_xor(ps, 32);
      l += ps;

      // ---- pack P -> f16 A-fragments (cross-half exchange)
      f16x8 pa[4];
#pragma unroll
      for (int st = 0; st < 2; ++st) {
        unsigned u[8];
#pragma unroll
        for (int g = 0; g < 4; ++g) {
          U32H2 a, bb;
          a.h  = pkrtz(p[st * 16 + 4 * g],     p[st * 16 + 4 * g + 1]);
          bb.h = pkrtz(p[st * 16 + 4 * g + 2], p[st * 16 + 4 * g + 3]);
          u[2 * g]     = a.u;
          u[2 * g + 1] = bb.u;
        }
#pragma unroll
        for (int cp = 0; cp < 2; ++cp) {
          const unsigned ua0 = u[4 * cp], ua1 = u[4 * cp + 1];
          const unsigned ub0 = u[4 * cp + 2], ub1 = u[4 * cp + 3];
          const unsigned t0 = (unsigned)__shfl_xor((int)(h2 ? ua0 : ub0), 32);
          const unsigned t1 = (unsigned)__shfl_xor((int)(h2 ? ua1 : ub1), 32);
          Frag f;
          f.u[0] = h2 ? t0 : ua0;
          f.u[1] = h2 ? t1 : ua1;
          f.u[2] = h2 ? ub0 : t0;
          f.u[3] = h2 ? ub1 : t1;
          pa[st * 2 + cp] = f.v;
        }
      }

      // ---- PV
      {
        const int sw = (qc & 7) << 4;
        __builtin_amdgcn_s_setprio(1);
#pragma unroll
        for (int c = 0; c < 4; ++c) {
          const int off = ((c << 5) + (h2 << 4)) ^ sw;
          const f16x8 vbl0 = *(const f16x8*)(Vt + (qc)      * 128 + off);
          const f16x8 vbl1 = *(const f16x8*)(Vt + (32 + qc) * 128 + off);
          o0 = mfma16(pa[c], vbl0, o0);
          o1 = mfma16(pa[c], vbl1, o1);
        }
        __builtin_amdgcn_s_setprio(0);
      }
    }

    if (pf) STAGE_WRITE(lds + (cur ^ 1) * BUFB);
    __syncthreads();
    cur ^= 1;
  }

  // ---- epilogue
  const float inv = 1.0f / l;
#pragma unroll
  for (int rr = 0; rr < 16; ++rr) {
    const int row = (rr & 3) + 8 * (rr >> 2) + 4 * h2;
    const float iv = __shfl(inv, row);
    float* op = O + (((size_t)(b * Ls + q0w + row) * Hh) + h) * Ee;
    op[qc]      = o0[rr] * iv;
    op[32 + qc] = o1[rr] * iv;
  }
}

extern "C" void kernel_launch(void* const* d_in, const int* in_sizes, int n_in,
                              void* d_out, int out_size, void* d_ws, size_t ws_size,
                              hipStream_t stream) {
  const float* Q = (const float*)d_in[0];
  const float* K = (const float*)d_in[1];
  const float* V = (const float*)d_in[2];
  float* O = (float*)d_out;
  (void)in_sizes; (void)n_in; (void)out_size; (void)d_ws; (void)ws_size;
  dim3 grid(Bb * Hh * (Ls / QT));  // 512 blocks, 4 waves each
  fattn<<<grid, dim3(256), 0, stream>>>(Q, K, V, O);
}

// Round 4
// 164.286 us; speedup vs baseline: 1.2628x; 1.0033x over previous
//
#include <hip/hip_runtime.h>

#define Bb 2
#define Ls 2048
#define Hh 16
#define Ee 64

#define QT 128    // q rows per block (8 waves x 16)
#define KT 64     // kv rows per tile
#define BUFB 24576  // Khi 8K | Klo 8K | Vt 8K

typedef __fp16 f16;
typedef __attribute__((ext_vector_type(2))) __fp16 f16x2;
typedef __attribute__((ext_vector_type(8))) __fp16 f16x8;
typedef __attribute__((ext_vector_type(4))) float  f32x4;

union Frag  { f16x8 v; f16x2 h[4]; unsigned int u[4]; };
union U32H2 { f16x2 h; unsigned int u; };

__device__ __forceinline__ f16x2 pkrtz(float a, float b) {
  return __builtin_amdgcn_cvt_pkrtz(a, b);
}
__device__ __forceinline__ f32x4 mfma16(f16x8 a, f16x8 b, f32x4 c) {
  return __builtin_amdgcn_mfma_f32_16x16x32_f16(a, b, c, 0, 0, 0);
}

// logits = 8*(q.k) -> exp2(S * 8*log2(e))
#define SC 11.541560327111707f

__launch_bounds__(512, 4)
__global__ void fattn(const float* __restrict__ Q, const float* __restrict__ K,
                      const float* __restrict__ V, float* __restrict__ O) {
  __shared__ __align__(16) char lds[2 * BUFB];

  const int tid  = threadIdx.x;
  const int lane = tid & 63;
  const int wid  = tid >> 6;     // 0..7
  const int g    = lane >> 4;    // k-chunk group 0..3
  const int q15  = lane & 15;    // owned q-col (S^T) / e-col (O)
  const int bid  = blockIdx.x;

  // complementary pairing: blocks (c, c+256) share a CU, qt sums to 15
  const int bh  = bid & 31;
  const int qtx = bid >> 5;
  const int qt  = (qtx < 8) ? qtx : 23 - qtx;
  const int b   = bh >> 4;
  const int h   = bh & 15;

  const int q0   = qt * QT;
  const int q0w  = q0 + wid * 16;
  const int qrow = q0w + q15;

  // ---- Q fragments (B operand: col=q15, k=8g+j+32c), f16 hi/lo
  f16x8 qh[2], ql[2];
  {
    const float* qp = Q + (((size_t)(b * Ls + qrow) * Hh) + h) * Ee + 8 * g;
#pragma unroll
    for (int c = 0; c < 2; ++c) {
      float x[8];
      *(float4*)&x[0] = *(const float4*)(qp + 32 * c);
      *(float4*)&x[4] = *(const float4*)(qp + 32 * c + 4);
      Frag fh, fl;
#pragma unroll
      for (int j = 0; j < 4; ++j) {
        f16x2 hi = pkrtz(x[2 * j], x[2 * j + 1]);
        fl.h[j] = pkrtz(x[2 * j] - (float)hi[0], x[2 * j + 1] - (float)hi[1]);
        fh.h[j] = hi;
      }
      qh[c] = fh.v;
      ql[c] = fl.v;
    }
  }

  // ---- staging roles (512 threads, 64x64 K + 64x64 V per tile)
  const int r    = tid >> 3;           // K row 0..63
  const int cbe  = (tid & 7) * 8;      // K col base (8 floats)
  const int kv0  = (tid & 31) * 2;     // V kv pair
  const int ec4  = (tid >> 5) * 4;     // V e cols (4)
  const float* kp0 = K + (((size_t)(b * Ls + r) * Hh) + h) * Ee + cbe;
  const float* vp0 = V + (((size_t)(b * Ls + kv0) * Hh) + h) * Ee + ec4;
  const int rowstride = Hh * Ee;       // 1024

  float4 ka0, ka1, va0, vb0;

#define STAGE_LOAD(KB)                                          \
  {                                                             \
    const float* kp = kp0 + (size_t)(KB) * rowstride;           \
    ka0 = *(const float4*)(kp);                                 \
    ka1 = *(const float4*)(kp + 4);                             \
    const float* vp = vp0 + (size_t)(KB) * rowstride;           \
    va0 = *(const float4*)(vp);                                 \
    vb0 = *(const float4*)(vp + rowstride);                     \
  }

#define STAGE_WRITE(BUF)                                        \
  {                                                             \
    char* Khi = (BUF);                                          \
    char* Klo = (BUF) + 8192;                                   \
    char* Vt  = (BUF) + 16384;                                  \
    float x[8];                                                 \
    *(float4*)&x[0] = ka0; *(float4*)&x[4] = ka1;               \
    Frag fh, fl;                                                \
    _Pragma("unroll")                                           \
    for (int j = 0; j < 4; ++j) {                               \
      f16x2 hi = pkrtz(x[2 * j], x[2 * j + 1]);                 \
      fl.h[j] = pkrtz(x[2 * j] - (float)hi[0],                  \
                      x[2 * j + 1] - (float)hi[1]);             \
      fh.h[j] = hi;                                             \
    }                                                           \
    const int sw = (r & 7) << 4;                                \
    *(f16x8*)(Khi + r * 128 + ((cbe * 2) ^ sw)) = fh.v;         \
    *(f16x8*)(Klo + r * 128 + ((cbe * 2) ^ sw)) = fl.v;         \
    _Pragma("unroll")                                           \
    for (int j = 0; j < 4; ++j) {                               \
      U32H2 pr;                                                 \
      pr.h = pkrtz(va0[j], vb0[j]);                             \
      const int e = ec4 + j;                                    \
      *(unsigned int*)(Vt + e * 128 + ((kv0 * 2) ^ ((e & 7) << 4))) = pr.u; \
    }                                                           \
  }

  f32x4 o0, o1, o2, o3;
#pragma unroll
  for (int i = 0; i < 4; ++i) { o0[i] = 0.f; o1[i] = 0.f; o2[i] = 0.f; o3[i] = 0.f; }
  float m = -3.0e38f, l = 0.f;

  const int NT = 2 * (qt + 1);

  STAGE_LOAD(0);
  STAGE_WRITE(lds);
  __syncthreads();
  int cur = 0;

  const int swr   = (q15 & 7) << 4;
  const int srcA  = q15 + ((g & 1) ? 32 : 0);
  const int srcB  = srcA + 16;
  const int srel  = g >> 1;
  const int lbase = lane & 48;

  for (int t = 0; t < NT; ++t) {
    const int kb = t * KT;
    const bool pf = (t + 1 < NT);
    if (pf) STAGE_LOAD(kb + KT);

    if (kb <= q0w + 15) {
      char* bufc = lds + cur * BUFB;
      char* Khi = bufc;
      char* Klo = bufc + 8192;
      char* Vt  = bufc + 16384;

      // ---- S^T = K * Q^T : 4 kv-subtiles x 2 k-chunks, hi/lo split
      f32x4 p4[4];
      __builtin_amdgcn_s_setprio(1);
#pragma unroll
      for (int st = 0; st < 4; ++st) {
        const char* kh = Khi + (16 * st + q15) * 128;
        const char* kl = Klo + (16 * st + q15) * 128;
        f32x4 acch, accl;
#pragma unroll
        for (int i = 0; i < 4; ++i) { acch[i] = 0.f; accl[i] = 0.f; }
#pragma unroll
        for (int c = 0; c < 2; ++c) {
          const int off = ((c << 6) + (g << 4)) ^ swr;
          f16x8 ah = *(const f16x8*)(kh + off);
          f16x8 al = *(const f16x8*)(kl + off);
          acch = mfma16(ah, qh[c], acch);
          accl = mfma16(ah, ql[c], accl);
          accl = mfma16(al, qh[c], accl);
        }
        p4[st] = acch + accl;
      }
      __builtin_amdgcn_s_setprio(0);

      // ---- causal mask (diagonal-overlap tiles only)
      if (kb + KT - 1 > q0w) {
#pragma unroll
        for (int st = 0; st < 4; ++st)
#pragma unroll
          for (int rg = 0; rg < 4; ++rg) {
            const int kv = kb + 16 * st + 4 * g + rg;
            if (kv > qrow) p4[st][rg] = -3.0e38f;
          }
      }

      // ---- online softmax (row q = q15; 4 g-copies combined via shfl_xor)
      f32x4 tv = p4[0];
#pragma unroll
      for (int i = 0; i < 4; ++i) tv[i] = fmaxf(fmaxf(p4[0][i], p4[1][i]), fmaxf(p4[2][i], p4[3][i]));
      float tm = fmaxf(fmaxf(tv[0], tv[1]), fmaxf(tv[2], tv[3]));
      tm = fmaxf(tm, __shfl_xor(tm, 16));
      tm = fmaxf(tm, __shfl_xor(tm, 32));

      if (__any(tm > m + 1.0f)) {
        const float mnew = fmaxf(m, tm);
        const float corr = __builtin_amdgcn_exp2f((m - mnew) * SC);
        l *= corr;
#pragma unroll
        for (int rg = 0; rg < 4; ++rg) {
          const float cr = __shfl(corr, lbase | (4 * g + rg));
          o0[rg] *= cr; o1[rg] *= cr; o2[rg] *= cr; o3[rg] *= cr;
        }
        m = mnew;
      }
      const float base = m * SC;
#pragma unroll
      for (int st = 0; st < 4; ++st)
#pragma unroll
        for (int rg = 0; rg < 4; ++rg)
          p4[st][rg] = __builtin_amdgcn_exp2f(p4[st][rg] * SC - base);

      {
        f32x4 sv = (p4[0] + p4[1]) + (p4[2] + p4[3]);
        float ps = (sv[0] + sv[1]) + (sv[2] + sv[3]);
        ps += __shfl_xor(ps, 16);
        ps += __shfl_xor(ps, 32);
        l += ps;
      }

      // ---- pack P -> A fragments (4-group redistribution: 8 shfl + 4 sel / chunk)
      unsigned int u[8];
#pragma unroll
      for (int st = 0; st < 4; ++st) {
        U32H2 w0, w1;
        w0.h = pkrtz(p4[st][0], p4[st][1]);
        w1.h = pkrtz(p4[st][2], p4[st][3]);
        u[2 * st]     = w0.u;
        u[2 * st + 1] = w1.u;
      }
      f16x8 pa[2];
#pragma unroll
      for (int c = 0; c < 2; ++c) {
        const unsigned a0 = (unsigned)__shfl((int)u[4 * c + 0], srcA);
        const unsigned a1 = (unsigned)__shfl((int)u[4 * c + 1], srcA);
        const unsigned a2 = (unsigned)__shfl((int)u[4 * c + 0], srcB);
        const unsigned a3 = (unsigned)__shfl((int)u[4 * c + 1], srcB);
        const unsigned b0 = (unsigned)__shfl((int)u[4 * c + 2], srcA);
        const unsigned b1 = (unsigned)__shfl((int)u[4 * c + 3], srcA);
        const unsigned b2 = (unsigned)__shfl((int)u[4 * c + 2], srcB);
        const unsigned b3 = (unsigned)__shfl((int)u[4 * c + 3], srcB);
        Frag f;
        f.u[0] = srel ? b0 : a0;
        f.u[1] = srel ? b1 : a1;
        f.u[2] = srel ? b2 : a2;
        f.u[3] = srel ? b3 : a3;
        pa[c] = f.v;
      }

      // ---- PV: O[q][e] += P * V (B from transposed V)
      __builtin_amdgcn_s_setprio(1);
#pragma unroll
      for (int c = 0; c < 2; ++c) {
        const int coff = ((c << 6) + (g << 4)) ^ swr;
        const f16x8 v0 = *(const f16x8*)(Vt + (q15)      * 128 + coff);
        const f16x8 v1 = *(const f16x8*)(Vt + (16 + q15) * 128 + coff);
        const f16x8 v2 = *(const f16x8*)(Vt + (32 + q15) * 128 + coff);
        const f16x8 v3 = *(const f16x8*)(Vt + (48 + q15) * 128 + coff);
        o0 = mfma16(pa[c], v0, o0);
        o1 = mfma16(pa[c], v1, o1);
        o2 = mfma16(pa[c], v2, o2);
        o3 = mfma16(pa[c], v3, o3);
      }
      __builtin_amdgcn_s_setprio(0);
    }

    if (pf) STAGE_WRITE(lds + (cur ^ 1) * BUFB);
    __syncthreads();
    cur ^= 1;
  }

  // ---- epilogue: normalize and store (O row = q0w+4g+rg, col = 16es+q15)
  const float inv = 1.0f / l;
#pragma unroll
  for (int rg = 0; rg < 4; ++rg) {
    const float iv = __shfl(inv, lbase | (4 * g + rg));
    float* op = O + (((size_t)(b * Ls + q0w + 4 * g + rg) * Hh) + h) * Ee + q15;
    op[0]  = o0[rg] * iv;
    op[16] = o1[rg] * iv;
    op[32] = o2[rg] * iv;
    op[48] = o3[rg] * iv;
  }
}

extern "C" void kernel_launch(void* const* d_in, const int* in_sizes, int n_in,
                              void* d_out, int out_size, void* d_ws, size_t ws_size,
                              hipStream_t stream) {
  const float* Q = (const float*)d_in[0];
  const float* K = (const float*)d_in[1];
  const float* V = (const float*)d_in[2];
  float* O = (float*)d_out;
  (void)in_sizes; (void)n_in; (void)out_size; (void)d_ws; (void)ws_size;
  fattn<<<dim3(Bb * Hh * (Ls / QT)), dim3(512), 0, stream>>>(Q, K, V, O);
}

// Round 5
// 163.182 us; speedup vs baseline: 1.2713x; 1.0068x over previous
//
#include <hip/hip_runtime.h>

#define Bb 2
#define Ls 2048
#define Hh 16
#define Ee 64

#define QT 64     // q rows per block (4 waves x 16)
#define KT 64     // kv rows per tile
#define BUFB 24576  // Khi 8K | Klo 8K | Vt 8K

typedef __fp16 f16;
typedef __attribute__((ext_vector_type(2))) __fp16 f16x2;
typedef __attribute__((ext_vector_type(8))) __fp16 f16x8;
typedef __attribute__((ext_vector_type(4))) float  f32x4;

union Frag  { f16x8 v; f16x2 h[4]; unsigned int u[4]; };
union U32H2 { f16x2 h; unsigned int u; };

__device__ __forceinline__ f16x2 pkrtz(float a, float b) {
  return __builtin_amdgcn_cvt_pkrtz(a, b);
}
__device__ __forceinline__ f32x4 mfma16(f16x8 a, f16x8 b, f32x4 c) {
  return __builtin_amdgcn_mfma_f32_16x16x32_f16(a, b, c, 0, 0, 0);
}

// logits = 8*(q.k) -> exp2(S * 8*log2(e))
#define SC 11.541560327111707f

__launch_bounds__(256, 3)
__global__ void fattn(const float* __restrict__ Q, const float* __restrict__ K,
                      const float* __restrict__ V, float* __restrict__ O) {
  __shared__ __align__(16) char lds[2 * BUFB];

  const int tid  = threadIdx.x;
  const int lane = tid & 63;
  const int wid  = tid >> 6;     // 0..3
  const int g    = lane >> 4;    // k-chunk group 0..3
  const int q15  = lane & 15;    // owned q-col (S^T) / e-col (O)
  const int bid  = blockIdx.x;

  // LPT: longest blocks (qt=31) first; same-bh blocks at stride 32 -> same XCD
  const int bh  = bid & 31;
  const int qt  = 31 - (bid >> 5);
  const int b   = bh >> 4;
  const int h   = bh & 15;

  const int q0   = qt * QT;
  const int q0w  = q0 + wid * 16;
  const int qrow = q0w + q15;

  // ---- Q fragments (B operand: col=q15, k=8g+j+32c), f16 hi/lo
  f16x8 qh[2], ql[2];
  {
    const float* qp = Q + (((size_t)(b * Ls + qrow) * Hh) + h) * Ee + 8 * g;
#pragma unroll
    for (int c = 0; c < 2; ++c) {
      float x[8];
      *(float4*)&x[0] = *(const float4*)(qp + 32 * c);
      *(float4*)&x[4] = *(const float4*)(qp + 32 * c + 4);
      Frag fh, fl;
#pragma unroll
      for (int j = 0; j < 4; ++j) {
        f16x2 hi = pkrtz(x[2 * j], x[2 * j + 1]);
        fl.h[j] = pkrtz(x[2 * j] - (float)hi[0], x[2 * j + 1] - (float)hi[1]);
        fh.h[j] = hi;
      }
      qh[c] = fh.v;
      ql[c] = fl.v;
    }
  }

  // ---- staging roles (256 threads: 16 K floats + 16 V floats each)
  const int r    = tid >> 2;           // K row 0..63
  const int cbe  = (tid & 3) * 16;     // K col base (16 floats)
  const int kv0  = (tid & 31) * 2;     // V kv pair
  const int ec   = tid >> 5;           // V e-col block 0..7
  const float* kp0 = K + (((size_t)(b * Ls + r) * Hh) + h) * Ee + cbe;
  const float* vp0 = V + (((size_t)(b * Ls + kv0) * Hh) + h) * Ee + ec * 8;
  const int rowstride = Hh * Ee;       // 1024

  float4 ka0, ka1, ka2, ka3, va0, va1, vb0, vb1;

#define STAGE_LOAD(KB)                                              \
  {                                                                 \
    const float* kp = kp0 + (size_t)(KB) * rowstride;               \
    ka0 = *(const float4*)(kp);                                     \
    ka1 = *(const float4*)(kp + 4);                                 \
    ka2 = *(const float4*)(kp + 8);                                 \
    ka3 = *(const float4*)(kp + 12);                                \
    const float* vp = vp0 + (size_t)(KB) * rowstride;               \
    va0 = *(const float4*)(vp);                                     \
    va1 = *(const float4*)(vp + 4);                                 \
    vb0 = *(const float4*)(vp + rowstride);                         \
    vb1 = *(const float4*)(vp + rowstride + 4);                     \
  }

#define STAGE_WRITE(BUF)                                            \
  {                                                                 \
    char* Khi = (BUF);                                              \
    char* Klo = (BUF) + 8192;                                       \
    char* Vt  = (BUF) + 16384;                                      \
    float x[16];                                                    \
    *(float4*)&x[0]  = ka0; *(float4*)&x[4]  = ka1;                 \
    *(float4*)&x[8]  = ka2; *(float4*)&x[12] = ka3;                 \
    Frag fh0, fl0, fh1, fl1;                                        \
    _Pragma("unroll")                                               \
    for (int j = 0; j < 4; ++j) {                                   \
      f16x2 hi0 = pkrtz(x[2 * j], x[2 * j + 1]);                    \
      fl0.h[j] = pkrtz(x[2 * j] - (float)hi0[0],                    \
                       x[2 * j + 1] - (float)hi0[1]);               \
      fh0.h[j] = hi0;                                               \
      f16x2 hi1 = pkrtz(x[8 + 2 * j], x[8 + 2 * j + 1]);            \
      fl1.h[j] = pkrtz(x[8 + 2 * j] - (float)hi1[0],                \
                       x[8 + 2 * j + 1] - (float)hi1[1]);           \
      fh1.h[j] = hi1;                                               \
    }                                                               \
    const int sw = (r & 7) << 4;                                    \
    char* dh = Khi + r * 128;                                       \
    char* dl = Klo + r * 128;                                       \
    *(f16x8*)(dh + ((cbe * 2) ^ sw))      = fh0.v;                  \
    *(f16x8*)(dh + ((cbe * 2 + 16) ^ sw)) = fh1.v;                  \
    *(f16x8*)(dl + ((cbe * 2) ^ sw))      = fl0.v;                  \
    *(f16x8*)(dl + ((cbe * 2 + 16) ^ sw)) = fl1.v;                  \
    float y0[8], y1[8];                                             \
    *(float4*)&y0[0] = va0; *(float4*)&y0[4] = va1;                 \
    *(float4*)&y1[0] = vb0; *(float4*)&y1[4] = vb1;                 \
    _Pragma("unroll")                                               \
    for (int j = 0; j < 8; ++j) {                                   \
      U32H2 pr;                                                     \
      pr.h = pkrtz(y0[j], y1[j]);                                   \
      const int e = ec * 8 + j;                                     \
      *(unsigned int*)(Vt + e * 128 + ((kv0 * 2) ^ ((e & 7) << 4))) = pr.u; \
    }                                                               \
  }

  f32x4 o0, o1, o2, o3;
#pragma unroll
  for (int i = 0; i < 4; ++i) { o0[i] = 0.f; o1[i] = 0.f; o2[i] = 0.f; o3[i] = 0.f; }
  float m = -3.0e38f, l = 0.f;

  const int NT = qt + 1;

  STAGE_LOAD(0);
  STAGE_WRITE(lds);
  __syncthreads();
  int cur = 0;

  const int swr   = (q15 & 7) << 4;
  const int srcA  = q15 + ((g & 1) ? 32 : 0);
  const int srcB  = srcA + 16;
  const int srel  = g >> 1;
  const int lbase = lane & 48;

  for (int t = 0; t < NT; ++t) {
    const int kb = t * KT;
    const bool pf = (t + 1 < NT);
    if (pf) STAGE_LOAD(kb + KT);

    {
      char* bufc = lds + cur * BUFB;
      char* Khi = bufc;
      char* Klo = bufc + 8192;
      char* Vt  = bufc + 16384;

      // ---- S^T = K * Q^T : 4 kv-subtiles x 2 k-chunks, hi/lo split
      f32x4 p4[4];
      __builtin_amdgcn_s_setprio(1);
#pragma unroll
      for (int st = 0; st < 4; ++st) {
        const char* kh = Khi + (16 * st + q15) * 128;
        const char* kl = Klo + (16 * st + q15) * 128;
        f32x4 acch, accl;
#pragma unroll
        for (int i = 0; i < 4; ++i) { acch[i] = 0.f; accl[i] = 0.f; }
#pragma unroll
        for (int c = 0; c < 2; ++c) {
          const int off = ((c << 6) + (g << 4)) ^ swr;
          f16x8 ah = *(const f16x8*)(kh + off);
          f16x8 al = *(const f16x8*)(kl + off);
          acch = mfma16(ah, qh[c], acch);
          accl = mfma16(ah, ql[c], accl);
          accl = mfma16(al, qh[c], accl);
        }
        p4[st] = acch + accl;
      }
      __builtin_amdgcn_s_setprio(0);

      // ---- causal mask (diagonal tile only)
      if (kb + KT - 1 > q0w) {
#pragma unroll
        for (int st = 0; st < 4; ++st)
#pragma unroll
          for (int rg = 0; rg < 4; ++rg) {
            const int kv = kb + 16 * st + 4 * g + rg;
            if (kv > qrow) p4[st][rg] = -3.0e38f;
          }
      }

      // ---- online softmax (row q = q15; 4 g-copies combined via shfl_xor)
      f32x4 tv;
#pragma unroll
      for (int i = 0; i < 4; ++i) tv[i] = fmaxf(fmaxf(p4[0][i], p4[1][i]), fmaxf(p4[2][i], p4[3][i]));
      float tm = fmaxf(fmaxf(tv[0], tv[1]), fmaxf(tv[2], tv[3]));
      tm = fmaxf(tm, __shfl_xor(tm, 16));
      tm = fmaxf(tm, __shfl_xor(tm, 32));

      if (__any(tm > m + 1.0f)) {
        const float mnew = fmaxf(m, tm);
        const float corr = __builtin_amdgcn_exp2f((m - mnew) * SC);
        l *= corr;
#pragma unroll
        for (int rg = 0; rg < 4; ++rg) {
          const float cr = __shfl(corr, lbase | (4 * g + rg));
          o0[rg] *= cr; o1[rg] *= cr; o2[rg] *= cr; o3[rg] *= cr;
        }
        m = mnew;
      }
      const float base = m * SC;
#pragma unroll
      for (int st = 0; st < 4; ++st)
#pragma unroll
        for (int rg = 0; rg < 4; ++rg)
          p4[st][rg] = __builtin_amdgcn_exp2f(p4[st][rg] * SC - base);

      {
        f32x4 sv = (p4[0] + p4[1]) + (p4[2] + p4[3]);
        float ps = (sv[0] + sv[1]) + (sv[2] + sv[3]);
        ps += __shfl_xor(ps, 16);
        ps += __shfl_xor(ps, 32);
        l += ps;
      }

      // ---- pack P -> A fragments (4-group redistribution)
      unsigned int u[8];
#pragma unroll
      for (int st = 0; st < 4; ++st) {
        U32H2 w0, w1;
        w0.h = pkrtz(p4[st][0], p4[st][1]);
        w1.h = pkrtz(p4[st][2], p4[st][3]);
        u[2 * st]     = w0.u;
        u[2 * st + 1] = w1.u;
      }
      f16x8 pa[2];
#pragma unroll
      for (int c = 0; c < 2; ++c) {
        const unsigned a0 = (unsigned)__shfl((int)u[4 * c + 0], srcA);
        const unsigned a1 = (unsigned)__shfl((int)u[4 * c + 1], srcA);
        const unsigned a2 = (unsigned)__shfl((int)u[4 * c + 0], srcB);
        const unsigned a3 = (unsigned)__shfl((int)u[4 * c + 1], srcB);
        const unsigned b0 = (unsigned)__shfl((int)u[4 * c + 2], srcA);
        const unsigned b1 = (unsigned)__shfl((int)u[4 * c + 3], srcA);
        const unsigned b2 = (unsigned)__shfl((int)u[4 * c + 2], srcB);
        const unsigned b3 = (unsigned)__shfl((int)u[4 * c + 3], srcB);
        Frag f;
        f.u[0] = srel ? b0 : a0;
        f.u[1] = srel ? b1 : a1;
        f.u[2] = srel ? b2 : a2;
        f.u[3] = srel ? b3 : a3;
        pa[c] = f.v;
      }

      // ---- PV: O[q][e] += P * V (B from transposed V)
      __builtin_amdgcn_s_setprio(1);
#pragma unroll
      for (int c = 0; c < 2; ++c) {
        const int coff = ((c << 6) + (g << 4)) ^ swr;
        const f16x8 v0 = *(const f16x8*)(Vt + (q15)      * 128 + coff);
        const f16x8 v1 = *(const f16x8*)(Vt + (16 + q15) * 128 + coff);
        const f16x8 v2 = *(const f16x8*)(Vt + (32 + q15) * 128 + coff);
        const f16x8 v3 = *(const f16x8*)(Vt + (48 + q15) * 128 + coff);
        o0 = mfma16(pa[c], v0, o0);
        o1 = mfma16(pa[c], v1, o1);
        o2 = mfma16(pa[c], v2, o2);
        o3 = mfma16(pa[c], v3, o3);
      }
      __builtin_amdgcn_s_setprio(0);
    }

    if (pf) STAGE_WRITE(lds + (cur ^ 1) * BUFB);
    __syncthreads();
    cur ^= 1;
  }

  // ---- epilogue: normalize and store (O row = q0w+4g+rg, col = 16es+q15)
  const float inv = 1.0f / l;
#pragma unroll
  for (int rg = 0; rg < 4; ++rg) {
    const float iv = __shfl(inv, lbase | (4 * g + rg));
    float* op = O + (((size_t)(b * Ls + q0w + 4 * g + rg) * Hh) + h) * Ee + q15;
    op[0]  = o0[rg] * iv;
    op[16] = o1[rg] * iv;
    op[32] = o2[rg] * iv;
    op[48] = o3[rg] * iv;
  }
}

extern "C" void kernel_launch(void* const* d_in, const int* in_sizes, int n_in,
                              void* d_out, int out_size, void* d_ws, size_t ws_size,
                              hipStream_t stream) {
  const float* Q = (const float*)d_in[0];
  const float* K = (const float*)d_in[1];
  const float* V = (const float*)d_in[2];
  float* O = (float*)d_out;
  (void)in_sizes; (void)n_in; (void)out_size; (void)d_ws; (void)ws_size;
  fattn<<<dim3(Bb * Hh * (Ls / QT)), dim3(256), 0, stream>>>(Q, K, V, O);
}

// Round 7
// 161.034 us; speedup vs baseline: 1.2883x; 1.0133x over previous
//
#include <hip/hip_runtime.h>

#define Bb 2
#define Ls 2048
#define Hh 16
#define Ee 64

#define QT 128    // q rows per block (4 waves x 32)
#define KT 64     // kv rows per tile
#define BUFB 24576  // Khi 8K | Klo 8K | Vt 8K

typedef __fp16 f16;
typedef __attribute__((ext_vector_type(2))) __fp16 f16x2;
typedef __attribute__((ext_vector_type(8))) __fp16 f16x8;
typedef __attribute__((ext_vector_type(16))) float  f32x16;

union Frag  { f16x8 v; f16x2 h[4]; unsigned int u[4]; };
union U32H2 { f16x2 h; unsigned int u; };

__device__ __forceinline__ f16x2 pkrtz(float a, float b) {
  return __builtin_amdgcn_cvt_pkrtz(a, b);
}
__device__ __forceinline__ f32x16 mfma32(f16x8 a, f16x8 b, f32x16 c) {
  return __builtin_amdgcn_mfma_f32_32x32x16_f16(a, b, c, 0, 0, 0);
}
__device__ __forceinline__ f32x16 zero16() {
  f32x16 z;
#pragma unroll
  for (int i = 0; i < 16; ++i) z[i] = 0.f;
  return z;
}

// logits = 8*(q.k) -> exp2(S * 8*log2(e))
#define SC 11.541560327111707f

// QK^T: S^T = K * Q^T  (A=K rows from LDS, B=Q regs), f16 hi/lo, 2 chains
#define QKT(BUF, S0, S1)                                          \
  {                                                               \
    const char* Khi_ = (BUF);                                     \
    const char* Klo_ = (BUF) + 8192;                              \
    _Pragma("unroll")                                             \
    for (int st_ = 0; st_ < 2; ++st_) {                           \
      const char* kh_ = Khi_ + (32 * st_ + qc) * 128;             \
      const char* kl_ = Klo_ + (32 * st_ + qc) * 128;             \
      f32x16 acch_ = zero16(), accl_ = zero16();                  \
      _Pragma("unroll")                                           \
      for (int c_ = 0; c_ < 4; ++c_) {                            \
        const int off_ = ((c_ << 5) + (h2 << 4)) ^ swr;           \
        f16x8 ah_ = *(const f16x8*)(kh_ + off_);                  \
        f16x8 al_ = *(const f16x8*)(kl_ + off_);                  \
        acch_ = mfma32(ah_, qh[c_], acch_);                       \
        accl_ = mfma32(ah_, ql[c_], accl_);                       \
        accl_ = mfma32(al_, qh[c_], accl_);                       \
      }                                                           \
      if (st_) S1 = acch_ + accl_; else S0 = acch_ + accl_;       \
    }                                                             \
  }

__launch_bounds__(256, 2)
__global__ void fattn(const float* __restrict__ Q, const float* __restrict__ K,
                      const float* __restrict__ V, float* __restrict__ O) {
  __shared__ __align__(16) char lds[2 * BUFB];

  const int tid  = threadIdx.x;
  const int lane = tid & 63;
  const int wid  = tid >> 6;     // 0..3
  const int h2   = lane >> 5;
  const int qc   = lane & 31;    // owned q-row (and e-row for V A-frags)
  const int bid  = blockIdx.x;

  // complementary pairing: blocks (c, c+256) share a CU, qt sums to 15
  const int bh  = bid & 31;
  const int qtx = bid >> 5;
  const int qt  = (qtx < 8) ? qtx : 23 - qtx;
  const int b   = bh >> 4;
  const int h   = bh & 15;

  const int q0   = qt * QT;
  const int q0w  = q0 + wid * 32;
  const int qrow = q0w + qc;
  const int swr  = (qc & 7) << 4;

  // ---- Q fragments (B operand: n=qc, k=16c+8h2+j), f16 hi/lo
  f16x8 qh[4], ql[4];
  {
    const float* qp = Q + (((size_t)(b * Ls + qrow) * Hh) + h) * Ee + h2 * 8;
#pragma unroll
    for (int c = 0; c < 4; ++c) {
      float x[8];
      *(float4*)&x[0] = *(const float4*)(qp + c * 16);
      *(float4*)&x[4] = *(const float4*)(qp + c * 16 + 4);
      Frag fh, fl;
#pragma unroll
      for (int j = 0; j < 4; ++j) {
        f16x2 hi = pkrtz(x[2 * j], x[2 * j + 1]);
        fl.h[j] = pkrtz(x[2 * j] - (float)hi[0], x[2 * j + 1] - (float)hi[1]);
        fh.h[j] = hi;
      }
      qh[c] = fh.v;
      ql[c] = fl.v;
    }
  }

  // ---- staging roles (256 threads: 16 K floats + 16 V floats each)
  const int r    = tid >> 2;           // K row 0..63
  const int cbe  = (tid & 3) * 16;     // K col base
  const int kv0  = (tid & 31) * 2;     // V kv pair
  const int ec   = tid >> 5;           // V e-col block 0..7
  const float* kp0 = K + (((size_t)(b * Ls + r) * Hh) + h) * Ee + cbe;
  const float* vp0 = V + (((size_t)(b * Ls + kv0) * Hh) + h) * Ee + ec * 8;
  const int rowstride = Hh * Ee;       // 1024

  float4 ka0, ka1, ka2, ka3, va0, va1, vb0, vb1;

#define STAGE_LOAD(KB)                                              \
  {                                                                 \
    const float* kp = kp0 + (size_t)(KB) * rowstride;               \
    ka0 = *(const float4*)(kp);                                     \
    ka1 = *(const float4*)(kp + 4);                                 \
    ka2 = *(const float4*)(kp + 8);                                 \
    ka3 = *(const float4*)(kp + 12);                                \
    const float* vp = vp0 + (size_t)(KB) * rowstride;               \
    va0 = *(const float4*)(vp);                                     \
    va1 = *(const float4*)(vp + 4);                                 \
    vb0 = *(const float4*)(vp + rowstride);                         \
    vb1 = *(const float4*)(vp + rowstride + 4);                     \
  }

#define STAGE_WRITE(BUF)                                            \
  {                                                                 \
    char* Khi = (BUF);                                              \
    char* Klo = (BUF) + 8192;                                       \
    char* Vt  = (BUF) + 16384;                                      \
    float x[16];                                                    \
    *(float4*)&x[0]  = ka0; *(float4*)&x[4]  = ka1;                 \
    *(float4*)&x[8]  = ka2; *(float4*)&x[12] = ka3;                 \
    Frag fh0, fl0, fh1, fl1;                                        \
    _Pragma("unroll")                                               \
    for (int j = 0; j < 4; ++j) {                                   \
      f16x2 hi0 = pkrtz(x[2 * j], x[2 * j + 1]);                    \
      fl0.h[j] = pkrtz(x[2 * j] - (float)hi0[0],                    \
                       x[2 * j + 1] - (float)hi0[1]);               \
      fh0.h[j] = hi0;                                               \
      f16x2 hi1 = pkrtz(x[8 + 2 * j], x[8 + 2 * j + 1]);            \
      fl1.h[j] = pkrtz(x[8 + 2 * j] - (float)hi1[0],                \
                       x[8 + 2 * j + 1] - (float)hi1[1]);           \
      fh1.h[j] = hi1;                                               \
    }                                                               \
    const int sw = (r & 7) << 4;                                    \
    char* dh = Khi + r * 128;                                       \
    char* dl = Klo + r * 128;                                       \
    *(f16x8*)(dh + ((cbe * 2) ^ sw))      = fh0.v;                  \
    *(f16x8*)(dh + ((cbe * 2 + 16) ^ sw)) = fh1.v;                  \
    *(f16x8*)(dl + ((cbe * 2) ^ sw))      = fl0.v;                  \
    *(f16x8*)(dl + ((cbe * 2 + 16) ^ sw)) = fl1.v;                  \
    float y0[8], y1[8];                                             \
    *(float4*)&y0[0] = va0; *(float4*)&y0[4] = va1;                 \
    *(float4*)&y1[0] = vb0; *(float4*)&y1[4] = vb1;                 \
    _Pragma("unroll")                                               \
    for (int j = 0; j < 8; ++j) {                                   \
      U32H2 pr;                                                     \
      pr.h = pkrtz(y0[j], y1[j]);                                   \
      const int e = ec * 8 + j;                                     \
      *(unsigned int*)(Vt + e * 128 + ((kv0 * 2) ^ ((e & 7) << 4))) = pr.u; \
    }                                                               \
  }

  f32x16 o0 = zero16(), o1 = zero16();
  float m = -3.0e38f, l = 0.f;

  const int NT = 2 * (qt + 1);

  // ---- prologue: stage tiles 0 and 1; compute S^T(0)
  STAGE_LOAD(0);
  STAGE_WRITE(lds);
  __syncthreads();
  STAGE_LOAD(KT);
  f32x16 s0, s1;
  QKT(lds, s0, s1);
  STAGE_WRITE(lds + BUFB);
  __syncthreads();

  for (int t = 0; t < NT; ++t) {
    const int kb = t * KT;
    char* cbuf = lds + (t & 1) * BUFB;
    char* nbuf = lds + ((t + 1) & 1) * BUFB;
    const bool pf2 = (t + 2 < NT);
    if (pf2) STAGE_LOAD(kb + 2 * KT);

    f32x16 n0 = s0, n1 = s1;
    if (kb <= q0w + 31) {
      __builtin_amdgcn_s_setprio(1);
      // QK^T of tile t+1 (independent MFMA stream; interleaves with softmax below)
      QKT(nbuf, n0, n1);

      // ---- softmax of tile t (all stats lane-local at q=qc)
      float p[32];
#pragma unroll
      for (int rr = 0; rr < 16; ++rr) { p[rr] = s0[rr]; p[16 + rr] = s1[rr]; }
      if (kb + KT - 1 > q0w) {
#pragma unroll
        for (int st = 0; st < 2; ++st)
#pragma unroll
          for (int rr = 0; rr < 16; ++rr) {
            const int kv = kb + 32 * st + ((rr & 3) + 8 * (rr >> 2) + 4 * h2);
            if (kv > qrow) p[st * 16 + rr] = -3.0e38f;
          }
      }
      float w[8];
#pragma unroll
      for (int i = 0; i < 8; ++i) w[i] = fmaxf(fmaxf(p[i], p[i + 8]), fmaxf(p[i + 16], p[i + 24]));
#pragma unroll
      for (int i = 0; i < 4; ++i) w[i] = fmaxf(w[i], w[i + 4]);
      float tm = fmaxf(fmaxf(w[0], w[1]), fmaxf(w[2], w[3]));
      tm = fmaxf(tm, __shfl_xor(tm, 32));

      if (__any(tm > m + 1.0f)) {
        const float mnew = fmaxf(m, tm);
        const float corr = __builtin_amdgcn_exp2f((m - mnew) * SC);
        l *= corr;
#pragma unroll
        for (int i = 0; i < 16; ++i) { o0[i] *= corr; o1[i] *= corr; }
        m = mnew;
      }
      const float base = m * SC;
#pragma unroll
      for (int i = 0; i < 32; ++i) p[i] = __builtin_amdgcn_exp2f(p[i] * SC - base);
      {
        float z[8];
#pragma unroll
        for (int i = 0; i < 8; ++i) z[i] = (p[i] + p[i + 8]) + (p[i + 16] + p[i + 24]);
#pragma unroll
        for (int i = 0; i < 4; ++i) z[i] += z[i + 4];
        float ps = (z[0] + z[1]) + (z[2] + z[3]);
        ps += __shfl_xor(ps, 32);
        l += ps;
      }

      // ---- pack P -> PV B-operand frags (8 shfl_xor(32) total)
      Frag pb[2][2];
#pragma unroll
      for (int st = 0; st < 2; ++st) {
        unsigned pk[8];
#pragma unroll
        for (int j = 0; j < 8; ++j) {
          U32H2 t2;
          t2.h = pkrtz(p[st * 16 + 2 * j], p[st * 16 + 2 * j + 1]);
          pk[j] = t2.u;
        }
        const unsigned r0 = (unsigned)__shfl_xor((int)(h2 ? pk[0] : pk[2]), 32);
        const unsigned r1 = (unsigned)__shfl_xor((int)(h2 ? pk[1] : pk[3]), 32);
        const unsigned r2 = (unsigned)__shfl_xor((int)(h2 ? pk[4] : pk[6]), 32);
        const unsigned r3 = (unsigned)__shfl_xor((int)(h2 ? pk[5] : pk[7]), 32);
        pb[st][0].u[0] = h2 ? r0 : pk[0];
        pb[st][0].u[1] = h2 ? r1 : pk[1];
        pb[st][0].u[2] = h2 ? pk[2] : r0;
        pb[st][0].u[3] = h2 ? pk[3] : r1;
        pb[st][1].u[0] = h2 ? r2 : pk[4];
        pb[st][1].u[1] = h2 ? r3 : pk[5];
        pb[st][1].u[2] = h2 ? pk[6] : r2;
        pb[st][1].u[3] = h2 ? pk[7] : r3;
      }

      // ---- PV: O (q on lanes) += V^T * P   (A=Vt rows e, B=P)
      {
        const char* Vt = cbuf + 16384;
#pragma unroll
        for (int st = 0; st < 2; ++st)
#pragma unroll
          for (int c2 = 0; c2 < 2; ++c2) {
            const int off = (64 * st + 32 * c2 + 16 * h2) ^ swr;
            const f16x8 va = *(const f16x8*)(Vt + qc * 128 + off);
            const f16x8 vb = *(const f16x8*)(Vt + (32 + qc) * 128 + off);
            o0 = mfma32(va, pb[st][c2].v, o0);
            o1 = mfma32(vb, pb[st][c2].v, o1);
          }
      }
      __builtin_amdgcn_s_setprio(0);
    }

    __syncthreads();                  // all reads of cbuf done
    if (pf2) STAGE_WRITE(cbuf);       // tile t+2 overwrites cbuf
    __syncthreads();                  // visible before QKT(t+2) next iter
    s0 = n0; s1 = n1;
  }

  // ---- epilogue: lane-local normalize; 8 float4 stores
  const float inv = 1.0f / l;
  float* op = O + (((size_t)(b * Ls + qrow) * Hh) + h) * Ee;
#pragma unroll
  for (int j = 0; j < 4; ++j) {
    float4 w0, w1;
    w0.x = o0[4 * j] * inv;     w0.y = o0[4 * j + 1] * inv;
    w0.z = o0[4 * j + 2] * inv; w0.w = o0[4 * j + 3] * inv;
    w1.x = o1[4 * j] * inv;     w1.y = o1[4 * j + 1] * inv;
    w1.z = o1[4 * j + 2] * inv; w1.w = o1[4 * j + 3] * inv;
    *(float4*)(op + 8 * j + 4 * h2)      = w0;
    *(float4*)(op + 32 + 8 * j + 4 * h2) = w1;
  }
}

extern "C" void kernel_launch(void* const* d_in, const int* in_sizes, int n_in,
                              void* d_out, int out_size, void* d_ws, size_t ws_size,
                              hipStream_t stream) {
  const float* Q = (const float*)d_in[0];
  const float* K = (const float*)d_in[1];
  const float* V = (const float*)d_in[2];
  float* O = (float*)d_out;
  (void)in_sizes; (void)n_in; (void)out_size; (void)d_ws; (void)ws_size;
  fattn<<<dim3(Bb * Hh * (Ls / QT)), dim3(256), 0, stream>>>(Q, K, V, O);
}